// Round 6
// baseline (102.309 us; speedup 1.0000x reference)
//
#include <hip/hip_runtime.h>
#include <math.h>

// ---------------------------------------------------------------------------
// VQ-VAE eval forward.  N=65536 points x K=1024 codes x D=64, fp32 in/out.
// Distances via f16x2 split-precision MFMA (16x16x32_f16), numerics as R2-R5:
//   z = zh + 2^-12 zl', e = eh + 2^-12 el'  (lo pre-scaled by 4096)
//   argmax key m = (zh.eh - esq/2) + 2^-12 (zh.el' + zl'.eh)
// R6: BARRIER-FREE main loop. No LDS staging: B fragments stream L2->regs
// (ping-pong prefetch), A persistent in regs (32 pts/wave), argmin completes
// in-wave (butterfly over the 16 code columns). 512 blocks x 256 thr.
// ---------------------------------------------------------------------------

#define QOUT_SZ  4194304            // 16*64*64*64
#define LOSS_OFF QOUT_SZ
#define IDX_OFF  (QOUT_SZ + 1)
#define PERP_OFF (QOUT_SZ + 1 + 65536)

typedef _Float16 f16x8 __attribute__((ext_vector_type(8)));
typedef _Float16 f16x4 __attribute__((ext_vector_type(4)));
typedef float    f32x4 __attribute__((ext_vector_type(4)));

// ws byte offsets
#define WS_EHI   0          // _Float16[65536] (128 KB)
#define WS_ELO   131072     // _Float16[65536] (128 KB)
#define WS_ESQ   262144     // float[1024]  (stores -0.5*||e||^2)
#define WS_HIST  266240     // float[1024]
#define WS_LOSS  270336     // float[512]

// ---------------------------------------------------------------------------
// Prep: split-convert embedding, esq[k] = -0.5*||e_k||^2, zero hist. 64 x 256.
// ---------------------------------------------------------------------------
__global__ void vq_pre(const float* __restrict__ emb,
                       _Float16* __restrict__ ehi, _Float16* __restrict__ elo,
                       float* __restrict__ esq, float* __restrict__ hist) {
    const int t = threadIdx.x;
    const int g = blockIdx.x * 256 + t;          // float4 unit 0..16383
    float4 v = ((const float4*)emb)[g];
    float xs[4] = {v.x, v.y, v.z, v.w};
    f16x4 hi, lo;
    float ss = 0.f;
#pragma unroll
    for (int j = 0; j < 4; ++j) {
        _Float16 h = (_Float16)xs[j];
        hi[j] = h;
        lo[j] = (_Float16)((xs[j] - (float)h) * 4096.0f);
        ss = fmaf(xs[j], xs[j], ss);
    }
    ((f16x4*)ehi)[g] = hi;
    ((f16x4*)elo)[g] = lo;
    ss += __shfl_xor(ss, 1, 64);
    ss += __shfl_xor(ss, 2, 64);
    ss += __shfl_xor(ss, 4, 64);
    ss += __shfl_xor(ss, 8, 64);
    if ((t & 15) == 0) esq[g >> 4] = -0.5f * ss;
    if (blockIdx.x < 4) hist[blockIdx.x * 256 + t] = 0.f;
}

// ---------------------------------------------------------------------------
// Main. 512 blocks x 256 threads (4 waves). Block owns 128 points (2 bh rows).
// Wave wv: hf = wv>>1 (h row), wside = (wv&1)*32; owns 32 points (2 MFMA
// tiles), sweeps ALL 1024 codes in 32 chunks of 32 (2 col-tiles of 16).
// B (ehi/elo frags) + esq prefetched global->reg, ping-pong; zero barriers
// until the tiny epilogue combine.
// ---------------------------------------------------------------------------
__launch_bounds__(256, 2)
__global__ void vq_main(const float* __restrict__ z,
                        const float* __restrict__ emb,
                        const _Float16* __restrict__ gehi,
                        const _Float16* __restrict__ gelo,
                        const float* __restrict__ gesq,
                        float* __restrict__ hist,
                        float* __restrict__ lossp,
                        float* __restrict__ out) {
    __shared__ int   idxs[128];
    __shared__ float redw[4];

    const int tid  = threadIdx.x;
    const int blk  = blockIdx.x;                  // 0..511
    const int b    = blk >> 5;
    const int h0   = (blk & 31) << 1;             // 2 h-rows per block
    const int lane = tid & 63;
    const int wv   = tid >> 6;                    // 0..3
    const int hf   = wv >> 1;                     // h row within block
    const int wside= (wv & 1) << 5;               // w half (0 / 32)
    const int col  = lane & 15;                   // B code column
    const int g    = lane >> 4;                   // 0..3 (K-slice quad)

    // ---- A fragments straight from global (one-time, per wave) ----
    const float* zb = z + (size_t)b * 262144 + (size_t)h0 * 64;
    const float* zrw = zb + hf * 64 + wside + col;
    f16x8 Ah[2][2], Al[2][2];
#pragma unroll
    for (int pt = 0; pt < 2; ++pt) {
#pragma unroll
        for (int m = 0; m < 2; ++m) {
#pragma unroll
            for (int j = 0; j < 8; ++j) {
                int c = m * 32 + g * 8 + j;
                float x = zrw[pt * 16 + (size_t)c * 4096];
                _Float16 hh = (_Float16)x;
                Ah[pt][m][j] = hh;
                Al[pt][m][j] = (_Float16)((x - (float)hh) * 4096.0f);
            }
        }
    }

    // per-lane invariant byte offset within a 16-code row-block
    const int inv = col * 128 + g * 16;           // code row 128 B, 16 B unit
    const char* gh = (const char*)gehi;
    const char* gl = (const char*)gelo;

    f16x8 B0h[2][2], B0l[2][2], B1h[2][2], B1l[2][2];
    float Q0[2], Q1[2];

#define LOADB(BH, BL, QQ, n) do {                                         \
        const int nb_ = (n) * 4096;                                       \
        _Pragma("unroll")                                                  \
        for (int ct_ = 0; ct_ < 2; ++ct_) {                                \
            _Pragma("unroll")                                              \
            for (int m_ = 0; m_ < 2; ++m_) {                               \
                const int o_ = nb_ + ct_ * 2048 + m_ * 64 + inv;           \
                BH[ct_][m_] = *(const f16x8*)(gh + o_);                    \
                BL[ct_][m_] = *(const f16x8*)(gl + o_);                    \
            }                                                              \
            QQ[ct_] = gesq[(n) * 32 + ct_ * 16 + col];                     \
        }                                                                  \
    } while (0)

#define COMPUTE(BH, BL, QQ, n) do {                                       \
        _Pragma("unroll")                                                  \
        for (int ct_ = 0; ct_ < 2; ++ct_) {                                \
            const float e2_  = QQ[ct_];                                    \
            const int   kidx_ = (n) * 32 + ct_ * 16 + col;                 \
            _Pragma("unroll")                                              \
            for (int pt_ = 0; pt_ < 2; ++pt_) {                            \
                f32x4 ah_ = {e2_, e2_, e2_, e2_};                          \
                f32x4 ax_ = {0.f, 0.f, 0.f, 0.f};                          \
                ah_ = __builtin_amdgcn_mfma_f32_16x16x32_f16(Ah[pt_][0], BH[ct_][0], ah_, 0, 0, 0); \
                ah_ = __builtin_amdgcn_mfma_f32_16x16x32_f16(Ah[pt_][1], BH[ct_][1], ah_, 0, 0, 0); \
                ax_ = __builtin_amdgcn_mfma_f32_16x16x32_f16(Ah[pt_][0], BL[ct_][0], ax_, 0, 0, 0); \
                ax_ = __builtin_amdgcn_mfma_f32_16x16x32_f16(Ah[pt_][1], BL[ct_][1], ax_, 0, 0, 0); \
                ax_ = __builtin_amdgcn_mfma_f32_16x16x32_f16(Al[pt_][0], BH[ct_][0], ax_, 0, 0, 0); \
                ax_ = __builtin_amdgcn_mfma_f32_16x16x32_f16(Al[pt_][1], BH[ct_][1], ax_, 0, 0, 0); \
                _Pragma("unroll")                                          \
                for (int r_ = 0; r_ < 4; ++r_) {                           \
                    float mv_ = fmaf(0x1p-12f, ax_[r_], ah_[r_]);          \
                    if (mv_ > best[pt_][r_]) {                             \
                        best[pt_][r_] = mv_; besti[pt_][r_] = kidx_;       \
                    }                                                      \
                }                                                          \
            }                                                              \
        }                                                                  \
    } while (0)

    float best[2][4];
    int   besti[2][4];
#pragma unroll
    for (int pt = 0; pt < 2; ++pt)
#pragma unroll
        for (int r = 0; r < 4; ++r) { best[pt][r] = -3.4e38f; besti[pt][r] = 0; }

    // ---- barrier-free K sweep: 32 chunks of 32 codes, ping-pong prefetch ----
    LOADB(B0h, B0l, Q0, 0);
    for (int sc = 0; sc < 30; sc += 2) {
        LOADB(B1h, B1l, Q1, sc + 1);
        COMPUTE(B0h, B0l, Q0, sc);
        LOADB(B0h, B0l, Q0, sc + 2);
        COMPUTE(B1h, B1l, Q1, sc + 1);
    }
    LOADB(B1h, B1l, Q1, 31);
    COMPUTE(B0h, B0l, Q0, 30);
    COMPUTE(B1h, B1l, Q1, 31);
#undef LOADB
#undef COMPUTE

    // ---- in-wave argmin over the 16 code columns (np first-min tie-break) ----
#pragma unroll
    for (int mask = 1; mask <= 8; mask <<= 1) {
#pragma unroll
        for (int pt = 0; pt < 2; ++pt)
#pragma unroll
            for (int r = 0; r < 4; ++r) {
                float ov = __shfl_xor(best[pt][r], mask, 64);
                int   oi = __shfl_xor(besti[pt][r], mask, 64);
                if (ov > best[pt][r] ||
                    (ov == best[pt][r] && oi < besti[pt][r])) {
                    best[pt][r] = ov; besti[pt][r] = oi;
                }
            }
    }
    if (col == 0) {                               // lanes 0,16,32,48
#pragma unroll
        for (int pt = 0; pt < 2; ++pt)
#pragma unroll
            for (int r = 0; r < 4; ++r)
                idxs[hf * 64 + wside + pt * 16 + g * 4 + r] = besti[pt][r];
    }
    __syncthreads();

    // ---- indices out + histogram ----
    if (tid < 128) {
        int bi = idxs[tid];
        atomicAdd(&hist[bi], 1.0f);               // exact int counts
        out[(size_t)IDX_OFF + (size_t)blk * 128 + tid] = (float)bi;
    }

    // ---- epilogue: quantized write (coalesced over w) + loss partial ----
    const int w  = tid & 63;
    const int cq = tid >> 6;                      // channels cq*16..cq*16+15
    float lsum = 0.f;
#pragma unroll
    for (int h2 = 0; h2 < 2; ++h2) {
        const int idx = idxs[h2 * 64 + w];
        const float* ev = emb + (size_t)idx * 64 + cq * 16;
        const float* zr = zb + h2 * 64 + w;
        float* outq = out + (size_t)b * 262144 + (size_t)(h0 + h2) * 64 + w;
#pragma unroll
        for (int i = 0; i < 4; ++i) {
            float4 qv = *(const float4*)(ev + i * 4);
            float q4[4] = {qv.x, qv.y, qv.z, qv.w};
#pragma unroll
            for (int jj = 0; jj < 4; ++jj) {
                int c = cq * 16 + i * 4 + jj;
                float zv = zr[(size_t)c * 4096];  // L2-hot re-read
                outq[(size_t)c * 4096] = q4[jj];
                float d = q4[jj] - zv;
                lsum = fmaf(d, d, lsum);
            }
        }
    }
#pragma unroll
    for (int off = 32; off > 0; off >>= 1)
        lsum += __shfl_xor(lsum, off, 64);
    if (lane == 0) redw[wv] = lsum;
    __syncthreads();
    if (tid == 0)
        lossp[blk] = redw[0] + redw[1] + redw[2] + redw[3];
}

// ---------------------------------------------------------------------------
// Finalize: loss + perplexity, fixed-order tree. 1 x 1024.
// ---------------------------------------------------------------------------
__global__ void vq_fin(const float* __restrict__ hist,
                       const float* __restrict__ lossp,
                       float* __restrict__ out) {
    __shared__ float sh[1024];
    __shared__ float sl[1024];
    int t = threadIdx.x;
    float hc = hist[t];
    float p  = hc * (1.0f / 65536.0f);
    sh[t] = p * logf(p + 1e-10f);
    sl[t] = (t < 512) ? lossp[t] : 0.f;
    __syncthreads();
    for (int s = 512; s > 0; s >>= 1) {
        if (t < s) { sh[t] += sh[t + s]; sl[t] += sl[t + s]; }
        __syncthreads();
    }
    if (t == 0) {
        out[LOSS_OFF] = 0.25f * sl[0] / (float)QOUT_SZ;
        out[PERP_OFF] = expf(-sh[0]);
    }
}

extern "C" void kernel_launch(void* const* d_in, const int* in_sizes, int n_in,
                              void* d_out, int out_size, void* d_ws, size_t ws_size,
                              hipStream_t stream) {
    const float* z   = (const float*)d_in[0];   // [16,64,64,64] fp32 NCHW
    const float* emb = (const float*)d_in[1];   // [1024,64] fp32
    float* out = (float*)d_out;
    char*  ws  = (char*)d_ws;

    _Float16* ehi   = (_Float16*)(ws + WS_EHI);
    _Float16* elo   = (_Float16*)(ws + WS_ELO);
    float*    esq   = (float*)(ws + WS_ESQ);
    float*    hist  = (float*)(ws + WS_HIST);
    float*    lossp = (float*)(ws + WS_LOSS);

    vq_pre<<<64, 256, 0, stream>>>(emb, ehi, elo, esq, hist);
    vq_main<<<512, 256, 0, stream>>>(z, emb, ehi, elo, esq, hist, lossp, out);
    vq_fin<<<1, 1024, 0, stream>>>(hist, lossp, out);
}

// Round 7
// 73.787 us; speedup vs baseline: 1.3865x; 1.3865x over previous
//
#include <hip/hip_runtime.h>
#include <math.h>

// ---------------------------------------------------------------------------
// VQ-VAE eval forward.  N=65536 points x K=1024 codes x D=64, fp32 in/out.
// Distances via f16x2 split-precision MFMA (16x16x32_f16), numerics as R2-R6:
//   z = zh + 2^-12 zl', e = eh + 2^-12 el'  (lo pre-scaled by 4096)
//   argmax key m = (zh.eh - esq/2) + 2^-12 (zh.el' + zl'.eh)
// R7 = R4 geometry (1024 blk x 256 thr, 4 waves = 2 pt-halves x 2 K-halves,
// 64-code chunks, verified-conflict-free XOR swizzle) + R5 pipeline depth
// (3-buffer LDS, 2 stages in flight, counted vmcnt(4) -- no full drains) +
// launch_bounds(256,3): 3 blocks/CU (12 waves), VGPR cap ~170 (no spill,
// scheduler headroom). Overlay arrays in buf1 (phase 15 reads buf0).
// ---------------------------------------------------------------------------

#define QOUT_SZ  4194304            // 16*64*64*64
#define LOSS_OFF QOUT_SZ
#define IDX_OFF  (QOUT_SZ + 1)
#define PERP_OFF (QOUT_SZ + 1 + 65536)

typedef _Float16 f16x8 __attribute__((ext_vector_type(8)));
typedef _Float16 f16x4 __attribute__((ext_vector_type(4)));
typedef float    f32x4 __attribute__((ext_vector_type(4)));

// ws byte offsets
#define WS_EHI   0          // _Float16[65536] (128 KB)
#define WS_ELO   131072     // _Float16[65536] (128 KB)
#define WS_ESQ   262144     // float[1024]  (stores -0.5*||e||^2)
#define WS_HIST  266240     // float[1024]
#define WS_LOSS  270336     // float[1024]

__device__ __forceinline__ void gll16(const void* g, void* l) {
    __builtin_amdgcn_global_load_lds(
        (const __attribute__((address_space(1))) void*)g,
        (__attribute__((address_space(3))) void*)l, 16, 0, 0);
}

// ---------------------------------------------------------------------------
// Prep: split-convert embedding, esq[k] = -0.5*||e_k||^2, zero hist. 64 x 256.
// ---------------------------------------------------------------------------
__global__ void vq_pre(const float* __restrict__ emb,
                       _Float16* __restrict__ ehi, _Float16* __restrict__ elo,
                       float* __restrict__ esq, float* __restrict__ hist) {
    const int t = threadIdx.x;
    const int g = blockIdx.x * 256 + t;          // float4 unit 0..16383
    float4 v = ((const float4*)emb)[g];
    float xs[4] = {v.x, v.y, v.z, v.w};
    f16x4 hi, lo;
    float ss = 0.f;
#pragma unroll
    for (int j = 0; j < 4; ++j) {
        _Float16 h = (_Float16)xs[j];
        hi[j] = h;
        lo[j] = (_Float16)((xs[j] - (float)h) * 4096.0f);
        ss = fmaf(xs[j], xs[j], ss);
    }
    ((f16x4*)ehi)[g] = hi;
    ((f16x4*)elo)[g] = lo;
    ss += __shfl_xor(ss, 1, 64);
    ss += __shfl_xor(ss, 2, 64);
    ss += __shfl_xor(ss, 4, 64);
    ss += __shfl_xor(ss, 8, 64);
    if ((t & 15) == 0) esq[g >> 4] = -0.5f * ss;
    if (blockIdx.x < 4) hist[blockIdx.x * 256 + t] = 0.f;
}

// ---------------------------------------------------------------------------
// Main. 1024 blocks x 256 threads (4 waves). Block owns 64 points (1 bh row).
// Wave (pg,ksel): pg = 32-pt half, ksel = 32-code half of each 64-code chunk.
// 16 chunks, 3-buffered, 2 stages in flight, counted vmcnt(4).
// ---------------------------------------------------------------------------
__launch_bounds__(256, 3)
__global__ void vq_main(const float* __restrict__ z,
                        const float* __restrict__ emb,
                        const _Float16* __restrict__ gehi,
                        const _Float16* __restrict__ gelo,
                        const float* __restrict__ gesq,
                        float* __restrict__ hist,
                        float* __restrict__ lossp,
                        float* __restrict__ out) {
    __shared__ __align__(16) char es[49152];   // 3 bufs x (hi 8K | lo 8K)
    __shared__ float esql[1024];               // -esq/2

    // post-loop overlays on buf1 (phase 15 reads buf0; buf1 idle after ph 13)
    float* candv = (float*)(es + 16384);       // [64][2]
    int*   candi = (int*)(es + 16384 + 512);   // [64][2]
    int*   idxs  = (int*)(es + 16384 + 1024);  // [64]
    float* redw  = (float*)(es + 16384 + 1280);// [4]

    const int tid  = threadIdx.x;
    const int blk  = blockIdx.x;               // = b*64 + h
    const int b    = blk >> 6;
    const int h    = blk & 63;
    const int lane = tid & 63;
    const int wv   = tid >> 6;                 // 0..3
    const int pg   = wv & 1;                   // point half (w 0-31 / 32-63)
    const int ksel = wv >> 1;                  // code half of chunk
    const int col  = lane & 15;
    const int g    = lane >> 4;                // 0..3

    // ---- stage -esq/2 into LDS (coalesced, once) ----
#pragma unroll
    for (int i = 0; i < 4; ++i) esql[tid + 256 * i] = gesq[tid + 256 * i];

    // ---- A fragments straight from global: lane col = point row ----
    const float* zb = z + (size_t)b * 262144 + (size_t)h * 64;
    const float* zrow = zb + pg * 32 + col;
    f16x8 Ah[2][2], Al[2][2];
#pragma unroll
    for (int pt = 0; pt < 2; ++pt) {
#pragma unroll
        for (int m = 0; m < 2; ++m) {
#pragma unroll
            for (int j = 0; j < 8; ++j) {
                int c = m * 32 + g * 8 + j;
                float x = zrow[pt * 16 + (size_t)c * 4096];
                _Float16 hh = (_Float16)x;
                Ah[pt][m][j] = hh;
                Al[pt][m][j] = (_Float16)((x - (float)hh) * 4096.0f);
            }
        }
    }

    // ---- staging geometry (verified conflict-free, R4): chunk = 64 codes ----
    // LDS dest linear (wave-uniform base + lane*16); global source
    // pre-XOR-swizzled (involution).
    const char* gh = (const char*)gehi;
    const char* gl = (const char*)gelo;
    const int u0 = tid, u1 = tid + 256;
    const int c0 = u0 >> 3, c1 = u1 >> 3;
    const size_t so0 = (size_t)c0 * 128 + (size_t)(((u0 & 7) ^ (c0 & 7)) * 16);
    const size_t so1 = (size_t)c1 * 128 + (size_t)(((u1 & 7) ^ (c1 & 7)) * 16);
    char* const dA = es + wv * 1024;           // wave-uniform dest base

#define STAGE(n, bo) do { \
        const size_t gb_ = (size_t)(n) * 8192; \
        char* d_ = dA + (bo); \
        gll16(gh + gb_ + so0, d_);            \
        gll16(gh + gb_ + so1, d_ + 4096);     \
        gll16(gl + gb_ + so0, d_ + 8192);     \
        gll16(gl + gb_ + so1, d_ + 12288);    \
    } while (0)

    // ---- per-lane B read offsets (swizzled, loop-invariant) ----
    int rb[2][2];
#pragma unroll
    for (int ct = 0; ct < 2; ++ct) {
        int cl = ksel * 32 + ct * 16 + col;
#pragma unroll
        for (int m = 0; m < 2; ++m)
            rb[ct][m] = cl * 128 + ((((m << 2) + g) ^ (cl & 7)) << 4);
    }

    float best[2][4];
    int   besti[2][4];
#pragma unroll
    for (int pt = 0; pt < 2; ++pt)
#pragma unroll
        for (int r = 0; r < 4; ++r) { best[pt][r] = -3.4e38f; besti[pt][r] = 0; }

    __syncthreads();                           // esql visible to all waves
    STAGE(0, 0);
    STAGE(1, 16384);

    // ---- k loop: 16 chunks of 64 codes, 3-buf, 2 stages in flight ----
    for (int sc = 0; sc < 16; ++sc) {
        // chunk sc's 4 loads are the oldest of <=8 outstanding
        if (sc < 15) asm volatile("s_waitcnt vmcnt(4)" ::: "memory");
        else         asm volatile("s_waitcnt vmcnt(0)" ::: "memory");
        __builtin_amdgcn_s_barrier();
        asm volatile("" ::: "memory");
        if (sc < 14) {
            int st = sc + 2; st -= (st >= 3) ? 3 : 0; st -= (st >= 3) ? 3 : 0;
            // (sc+2) % 3 without div: sc+2 in [2,17] -> fold twice is wrong;
            // compute directly:
        }
        {
            int nxt = sc + 2;
            if (nxt < 16) {
                int bo = nxt - (nxt / 3) * 3;          // (sc+2) % 3
                STAGE(nxt, bo * 16384);
            }
        }

        const int cb = sc - (sc / 3) * 3;              // sc % 3
        const char* bp = es + cb * 16384;
        const int kb = sc * 64 + ksel * 32;
#pragma unroll
        for (int ct = 0; ct < 2; ++ct) {
            const int  kcol = kb + ct * 16 + col;
            const float e2  = esql[kcol];
            f16x8 Bh0 = *(const f16x8*)(bp + rb[ct][0]);
            f16x8 Bh1 = *(const f16x8*)(bp + rb[ct][1]);
            f16x8 Bl0 = *(const f16x8*)(bp + 8192 + rb[ct][0]);
            f16x8 Bl1 = *(const f16x8*)(bp + 8192 + rb[ct][1]);
#pragma unroll
            for (int pt = 0; pt < 2; ++pt) {
                f32x4 ah = {e2, e2, e2, e2};
                f32x4 ax = {0.f, 0.f, 0.f, 0.f};
                ah = __builtin_amdgcn_mfma_f32_16x16x32_f16(Ah[pt][0], Bh0, ah, 0, 0, 0);
                ah = __builtin_amdgcn_mfma_f32_16x16x32_f16(Ah[pt][1], Bh1, ah, 0, 0, 0);
                ax = __builtin_amdgcn_mfma_f32_16x16x32_f16(Ah[pt][0], Bl0, ax, 0, 0, 0);
                ax = __builtin_amdgcn_mfma_f32_16x16x32_f16(Ah[pt][1], Bl1, ax, 0, 0, 0);
                ax = __builtin_amdgcn_mfma_f32_16x16x32_f16(Al[pt][0], Bh0, ax, 0, 0, 0);
                ax = __builtin_amdgcn_mfma_f32_16x16x32_f16(Al[pt][1], Bh1, ax, 0, 0, 0);
#pragma unroll
                for (int r = 0; r < 4; ++r) {
                    float mval = fmaf(0x1p-12f, ax[r], ah[r]);
                    if (mval > best[pt][r]) { best[pt][r] = mval; besti[pt][r] = kcol; }
                }
            }
        }
    }
#undef STAGE

    // ---- in-wave argmin over 16 code-cols (butterfly, np tie-break) ----
#pragma unroll
    for (int mask = 1; mask <= 8; mask <<= 1) {
#pragma unroll
        for (int pt = 0; pt < 2; ++pt)
#pragma unroll
            for (int r = 0; r < 4; ++r) {
                float ov = __shfl_xor(best[pt][r], mask, 64);
                int   oi = __shfl_xor(besti[pt][r], mask, 64);
                if (ov > best[pt][r] ||
                    (ov == best[pt][r] && oi < besti[pt][r])) {
                    best[pt][r] = ov; besti[pt][r] = oi;
                }
            }
    }
    // overlay lives in buf1: phase-15 readers use buf0 only, and buf1's last
    // readers (phase 13) all passed the phase-15 barrier already -> safe.
    if (col == 0) {
#pragma unroll
        for (int pt = 0; pt < 2; ++pt)
#pragma unroll
            for (int r = 0; r < 4; ++r) {
                int p = pg * 32 + pt * 16 + g * 4 + r;
                candv[p * 2 + ksel] = best[pt][r];
                candi[p * 2 + ksel] = besti[pt][r];
            }
    }
    __syncthreads();

    // ---- combine the two K-halves, write idx, histogram ----
    if (tid < 64) {
        float v0 = candv[tid * 2],     v1 = candv[tid * 2 + 1];
        int   i0 = candi[tid * 2],     i1 = candi[tid * 2 + 1];
        int bi = (v1 > v0 || (v1 == v0 && i1 < i0)) ? i1 : i0;
        idxs[tid] = bi;
        atomicAdd(&hist[bi], 1.0f);            // exact int counts
        out[(size_t)IDX_OFF + blk * 64 + tid] = (float)bi;
    }
    __syncthreads();

    // ---- epilogue: quantized write (coalesced over w) + loss partial ----
    const int w  = tid & 63;
    const int cq = tid >> 6;                   // channels cq*16..cq*16+15
    const int idx = idxs[w];
    const float* ev = emb + (size_t)idx * 64 + cq * 16;
    const float* zr = zb + w;
    float* outq = out + (size_t)b * 262144 + (size_t)h * 64 + w;
    float lsum = 0.f;
#pragma unroll
    for (int i = 0; i < 4; ++i) {
        float4 qv = *(const float4*)(ev + i * 4);
        float q4[4] = {qv.x, qv.y, qv.z, qv.w};
#pragma unroll
        for (int jj = 0; jj < 4; ++jj) {
            int c = cq * 16 + i * 4 + jj;
            float zv = zr[(size_t)c * 4096];   // L3-hot re-read
            outq[(size_t)c * 4096] = q4[jj];
            float d = q4[jj] - zv;
            lsum = fmaf(d, d, lsum);
        }
    }
#pragma unroll
    for (int off = 32; off > 0; off >>= 1)
        lsum += __shfl_xor(lsum, off, 64);
    if (lane == 0) redw[wv] = lsum;
    __syncthreads();
    if (tid == 0)
        lossp[blk] = redw[0] + redw[1] + redw[2] + redw[3];
}

// ---------------------------------------------------------------------------
// Finalize: loss + perplexity, fixed-order tree. 1 x 1024.
// ---------------------------------------------------------------------------
__global__ void vq_fin(const float* __restrict__ hist,
                       const float* __restrict__ lossp,
                       float* __restrict__ out) {
    __shared__ float sh[1024];
    __shared__ float sl[1024];
    int t = threadIdx.x;
    float hc = hist[t];
    float p  = hc * (1.0f / 65536.0f);
    sh[t] = p * logf(p + 1e-10f);
    sl[t] = lossp[t];
    __syncthreads();
    for (int s = 512; s > 0; s >>= 1) {
        if (t < s) { sh[t] += sh[t + s]; sl[t] += sl[t + s]; }
        __syncthreads();
    }
    if (t == 0) {
        out[LOSS_OFF] = 0.25f * sl[0] / (float)QOUT_SZ;
        out[PERP_OFF] = expf(-sh[0]);
    }
}

extern "C" void kernel_launch(void* const* d_in, const int* in_sizes, int n_in,
                              void* d_out, int out_size, void* d_ws, size_t ws_size,
                              hipStream_t stream) {
    const float* z   = (const float*)d_in[0];   // [16,64,64,64] fp32 NCHW
    const float* emb = (const float*)d_in[1];   // [1024,64] fp32
    float* out = (float*)d_out;
    char*  ws  = (char*)d_ws;

    _Float16* ehi   = (_Float16*)(ws + WS_EHI);
    _Float16* elo   = (_Float16*)(ws + WS_ELO);
    float*    esq   = (float*)(ws + WS_ESQ);
    float*    hist  = (float*)(ws + WS_HIST);
    float*    lossp = (float*)(ws + WS_LOSS);

    vq_pre<<<64, 256, 0, stream>>>(emb, ehi, elo, esq, hist);
    vq_main<<<1024, 256, 0, stream>>>(z, emb, ehi, elo, esq, hist, lossp, out);
    vq_fin<<<1, 1024, 0, stream>>>(hist, lossp, out);
}